// Round 9
// baseline (225.761 us; speedup 1.0000x reference)
//
#include <hip/hip_runtime.h>

// ConvCapsMatrix EM routing, MI355X. Inputs FP32, output FP32 (reference
// output dtype is float32 — R8 proved prior failures were bf16-into-fp32
// buffer packing, not math). One workgroup per position (576 x 256),
// thread=(o=t&31, ng=t>>5). Per iteration: pass M (Ra + sum Ra*V -> mu),
// pass S (sum Ra*(V-mu)^2 -> sig2). Variance is a sum of non-negatives.

#define NN    288
#define EPSV  1e-8f

__device__ __forceinline__ void compute_votes(const float* __restrict__ Wt,
                                              const float* __restrict__ xp_s,
                                              int n, int o, float* __restrict__ V)
{
  // W[k,l,c,o,y,z] flat = (n*32+o)*16 + y*4+z
  float Wf[16];
  {
    const float* wp = Wt + (((n << 5) + o) << 4);
#pragma unroll
    for (int i = 0; i < 4; ++i) {
      const float4 q = *(const float4*)(wp + (i << 2));
      Wf[i*4+0]=q.x; Wf[i*4+1]=q.y; Wf[i*4+2]=q.z; Wf[i*4+3]=q.w;
    }
  }
  float xv[16];
  {
    const float* xr = xp_s + (n << 4);
#pragma unroll
    for (int i = 0; i < 4; ++i) {
      const float4 q = *(const float4*)(xr + (i << 2));
      xv[i*4+0]=q.x; xv[i*4+1]=q.y; xv[i*4+2]=q.z; xv[i*4+3]=q.w;
    }
  }
#pragma unroll
  for (int xi = 0; xi < 4; ++xi)
#pragma unroll
    for (int z = 0; z < 4; ++z)
      V[xi*4+z] = fmaf(xv[xi*4+0], Wf[z],
                  fmaf(xv[xi*4+1], Wf[4+z],
                  fmaf(xv[xi*4+2], Wf[8+z],
                       xv[xi*4+3]* Wf[12+z])));
}

__global__ __launch_bounds__(256, 2) void caps_em_kernel(
    const float* __restrict__ X, const float* __restrict__ A, const float* __restrict__ Wt,
    const float* __restrict__ Bu, const float* __restrict__ Ba,
    float* __restrict__ Out)
{
  __shared__ float xp_s[NN*16];   // patch poses
  __shared__ float a_s[NN];       // patch activations
  __shared__ float part[4*544];   // per-wave partials (rows padded to 17)
  __shared__ float prs[4*32];     // per-wave partials of sum Ra
  __shared__ float mu_t[512];     // mu[p][o]
  __shared__ float isig_t[512];   // 1/sig2[p][o]
  __shared__ float lsig_t[512];   // log sig2[p][o]
  __shared__ float la_s[32];      // log(a_out+eps)
  __shared__ float slog_s[32];    // sum_p log sig2
  __shared__ float aout_s[32];

  const int t    = threadIdx.x;
  const int o    = t & 31;
  const int ng   = t >> 5;
  const int wv   = t >> 6;
  const int lane = t & 63;

  const int pos = blockIdx.x;
  const int b  = pos / 144;
  const int r_ = pos - b*144;
  const int h  = r_ / 12;
  const int w  = r_ - (r_/12)*12;

  // ---- stage pose patch: x[b,h+k,w+l,c,p] -> xp_s[(kl*32+c)*16+p]
  for (int i = t; i < 1152; i += 256) {
    const int e   = i << 2;
    const int kl  = e >> 9;
    const int rem = e & 511;
    const int hy = h + kl/3, wx = w + (kl - (kl/3)*3);
    const float4 q = *(const float4*)(X + ((((b*14 + hy)*14 + wx) << 9) + rem));
    *(float4*)(xp_s + (kl << 9) + rem) = q;
  }
  for (int i = t; i < NN; i += 256) {
    const int kl = i >> 5, c = i & 31;
    const int hy = h + kl/3, wx = w + (kl - (kl/3)*3);
    a_s[i] = A[((b*14 + hy)*14 + wx)*32 + c];
  }
  __syncthreads();

  // per-thread cached routing state (o fixed per thread)
  float mu_r[16], isig_r[16];
  float la_r = 0.f, slog_r = 0.f;
#pragma unroll
  for (int p = 0; p < 16; ++p) { mu_r[p] = 0.f; isig_r[p] = 0.f; }
  float ra_r[36];

  for (int it = 0; it < 3; ++it) {
    // ================= pass M: Ra and sum Ra*V =================
    float S1[16];
#pragma unroll
    for (int p = 0; p < 16; ++p) S1[p] = 0.f;
    float rs = 0.f;

#pragma unroll 1
    for (int j = 0; j < 36; ++j) {
      const int n = ng + (j << 3);
      float V[16];
      compute_votes(Wt, xp_s, n, o, V);

      float ra;
      if (it == 0) {
        ra = a_s[n] * (1.0f/32.0f);
      } else {
        // logp = -0.5 * ( sum_p (V-mu)^2*isig + slog )
        float q = slog_r;
#pragma unroll
        for (int p = 0; p < 16; ++p) {
          const float d = V[p] - mu_r[p];
          q = fmaf(d*d, isig_r[p], q);
        }
        float z = la_r - 0.5f*q;
        // softmax over the 32 o's (one half-wave holds all o for this n)
        float m = z;
#pragma unroll
        for (int msk = 16; msk >= 1; msk >>= 1) m = fmaxf(m, __shfl_xor(m, msk));
        float ev = expf(z - m);
        float s = ev;
#pragma unroll
        for (int msk = 16; msk >= 1; msk >>= 1) s += __shfl_xor(s, msk);
        ra = (ev / s) * a_s[n];
      }
      ra_r[j] = ra;
      rs += ra;
#pragma unroll
      for (int p = 0; p < 16; ++p) S1[p] = fmaf(ra, V[p], S1[p]);
    }

#pragma unroll
    for (int p = 0; p < 16; ++p) S1[p] += __shfl_xor(S1[p], 32);
    rs += __shfl_xor(rs, 32);
    if (lane < 32) {
      float* p1 = part + wv*544 + o*17;
#pragma unroll
      for (int p = 0; p < 16; ++p) p1[p] = S1[p];
      prs[wv*32 + o] = rs;
    }
    __syncthreads();

    // ---- E1a: mu per (o,p)
    for (int e = t; e < 512; e += 256) {
      const int pi = e >> 5, oo = e & 31;
      float s1 = 0.f, rsum = EPSV;
#pragma unroll
      for (int w4 = 0; w4 < 4; ++w4) {
        s1   += part[w4*544 + oo*17 + pi];
        rsum += prs[w4*32 + oo];
      }
      mu_t[pi*32 + oo] = s1 / rsum;
    }
    __syncthreads();

#pragma unroll
    for (int p = 0; p < 16; ++p) mu_r[p] = mu_t[p*32 + o];

    // ================= pass S: sum Ra*(V-mu)^2 (non-negative) =================
    float S2[16];
#pragma unroll
    for (int p = 0; p < 16; ++p) S2[p] = 0.f;

#pragma unroll 1
    for (int j = 0; j < 36; ++j) {
      const int n = ng + (j << 3);
      float V[16];
      compute_votes(Wt, xp_s, n, o, V);
      const float ra = ra_r[j];
#pragma unroll
      for (int p = 0; p < 16; ++p) {
        const float d = V[p] - mu_r[p];
        S2[p] = fmaf(ra*d, d, S2[p]);
      }
    }

#pragma unroll
    for (int p = 0; p < 16; ++p) S2[p] += __shfl_xor(S2[p], 32);
    if (lane < 32) {
      float* p2 = part + wv*544 + o*17;
#pragma unroll
      for (int p = 0; p < 16; ++p) p2[p] = S2[p];
    }
    __syncthreads();

    // ---- E1b: sig2, log, inverse
    for (int e = t; e < 512; e += 256) {
      const int pi = e >> 5, oo = e & 31;
      float s2 = 0.f, rsum = EPSV;
#pragma unroll
      for (int w4 = 0; w4 < 4; ++w4) {
        s2   += part[w4*544 + oo*17 + pi];
        rsum += prs[w4*32 + oo];
      }
      const float sg = s2 / rsum + EPSV;   // >= eps, strictly positive
      isig_t[pi*32 + oo] = 1.0f / sg;
      lsig_t[pi*32 + oo] = logf(sg);
    }
    __syncthreads();

    // ---- E2: cost, a_out per o
    if (t < 32) {
      float rsum = EPSV;
#pragma unroll
      for (int w4 = 0; w4 < 4; ++w4) rsum += prs[w4*32 + t];
      float slog = 0.f;
#pragma unroll
      for (int p = 0; p < 16; ++p) slog += lsig_t[p*32 + t];
      const float bu = Bu[t];
      const float ba = Ba[t];
      const float cost = rsum * (16.0f*bu + 0.5f*slog);
      const float av = 1.0f / (1.0f + expf(-(ba - cost)));   // LAM=1
      aout_s[t] = av;
      la_s[t]   = logf(av + EPSV);
      slog_s[t] = slog;
    }
    __syncthreads();

    if (it < 2) {
#pragma unroll
      for (int p = 0; p < 16; ++p) isig_r[p] = isig_t[p*32 + o];
      slog_r = slog_s[o];
      la_r   = la_s[o];
    }
  }

  // ---- outputs (fp32): pose = mu (B,Ho,Wo,OC,M,M) then a_out (B,Ho,Wo,OC)
  for (int e = t; e < 512; e += 256) {
    const int oo = e >> 4, pi = e & 15;
    Out[pos*512 + e] = mu_t[pi*32 + oo];
  }
  if (t < 32) Out[294912 + pos*32 + t] = aout_s[t];
}

extern "C" void kernel_launch(void* const* d_in, const int* in_sizes, int n_in,
                              void* d_out, int out_size, void* d_ws, size_t ws_size,
                              hipStream_t stream) {
  (void)in_sizes; (void)n_in; (void)d_ws; (void)ws_size; (void)out_size;
  const float* X  = (const float*)d_in[0];
  const float* A  = (const float*)d_in[1];
  const float* Wt = (const float*)d_in[2];
  const float* Bu = (const float*)d_in[3];
  const float* Ba = (const float*)d_in[4];
  float* Out = (float*)d_out;
  hipLaunchKernelGGL(caps_em_kernel, dim3(576), dim3(256), 0, stream,
                     X, A, Wt, Bu, Ba, Out);
}

// Round 10
// 180.438 us; speedup vs baseline: 1.2512x; 1.2512x over previous
//
#include <hip/hip_runtime.h>

// ConvCapsMatrix EM routing, MI355X. Inputs FP32, output FP32.
// R10: (a) fused variance sig2 = E[V^2]-mu^2 (+clamp) -> 3 vote passes, not 6;
//      (b) 512-thread blocks (16 n-groups, j=18) -> 2x resident threads.
// One workgroup per position (576 x 512), thread=(o=t&31, ng=t>>5).

#define NN    288
#define EPSV  1e-8f

__device__ __forceinline__ void compute_votes(const float* __restrict__ Wt,
                                              const float* __restrict__ xp_s,
                                              int n, int o, float* __restrict__ V)
{
  // W[k,l,c,o,y,z] flat = (n*32+o)*16 + y*4+z
  float Wf[16];
  {
    const float* wp = Wt + (((n << 5) + o) << 4);
#pragma unroll
    for (int i = 0; i < 4; ++i) {
      const float4 q = *(const float4*)(wp + (i << 2));
      Wf[i*4+0]=q.x; Wf[i*4+1]=q.y; Wf[i*4+2]=q.z; Wf[i*4+3]=q.w;
    }
  }
  float xv[16];
  {
    const float* xr = xp_s + (n << 4);
#pragma unroll
    for (int i = 0; i < 4; ++i) {
      const float4 q = *(const float4*)(xr + (i << 2));
      xv[i*4+0]=q.x; xv[i*4+1]=q.y; xv[i*4+2]=q.z; xv[i*4+3]=q.w;
    }
  }
#pragma unroll
  for (int xi = 0; xi < 4; ++xi)
#pragma unroll
    for (int z = 0; z < 4; ++z)
      V[xi*4+z] = fmaf(xv[xi*4+0], Wf[z],
                  fmaf(xv[xi*4+1], Wf[4+z],
                  fmaf(xv[xi*4+2], Wf[8+z],
                       xv[xi*4+3]* Wf[12+z])));
}

__global__ __launch_bounds__(512, 4) void caps_em_kernel(
    const float* __restrict__ X, const float* __restrict__ A, const float* __restrict__ Wt,
    const float* __restrict__ Bu, const float* __restrict__ Ba,
    float* __restrict__ Out)
{
  __shared__ float xp_s[NN*16];   // patch poses               18.4 KB
  __shared__ float a_s[NN];       // patch activations          1.2 KB
  __shared__ float part1[8*544];  // per-wave sum Ra*V   (pad17) 17.4 KB
  __shared__ float part2[8*544];  // per-wave sum Ra*V^2 (pad17) 17.4 KB
  __shared__ float prs[8*32];     // per-wave sum Ra             1 KB
  __shared__ float mu_t[512];     // mu[p][o]
  __shared__ float isig_t[512];   // 1/sig2[p][o]
  __shared__ float lsig_t[512];   // log sig2[p][o]
  __shared__ float la_s[32];      // log(a_out+eps)
  __shared__ float slog_s[32];    // sum_p log sig2
  __shared__ float aout_s[32];

  const int t    = threadIdx.x;
  const int o    = t & 31;
  const int ng   = t >> 5;        // 0..15
  const int wv   = t >> 6;        // 0..7
  const int lane = t & 63;

  const int pos = blockIdx.x;
  const int b  = pos / 144;
  const int r_ = pos - b*144;
  const int h  = r_ / 12;
  const int w  = r_ - (r_/12)*12;

  // ---- stage pose patch: x[b,h+k,w+l,c,p] -> xp_s[(kl*32+c)*16+p]
  for (int i = t; i < 1152; i += 512) {
    const int e   = i << 2;
    const int kl  = e >> 9;
    const int rem = e & 511;
    const int hy = h + kl/3, wx = w + (kl - (kl/3)*3);
    const float4 q = *(const float4*)(X + ((((b*14 + hy)*14 + wx) << 9) + rem));
    *(float4*)(xp_s + (kl << 9) + rem) = q;
  }
  for (int i = t; i < NN; i += 512) {
    const int kl = i >> 5, c = i & 31;
    const int hy = h + kl/3, wx = w + (kl - (kl/3)*3);
    a_s[i] = A[((b*14 + hy)*14 + wx)*32 + c];
  }
  __syncthreads();

  // per-thread cached routing state (o fixed per thread)
  float mu_r[16], isig_r[16];
  float la_r = 0.f, slog_r = 0.f;
#pragma unroll
  for (int p = 0; p < 16; ++p) { mu_r[p] = 0.f; isig_r[p] = 0.f; }

  for (int it = 0; it < 3; ++it) {
    // ========== single fused pass: Ra, sum Ra*V, sum Ra*V^2 ==========
    float S1[16], S2[16];
#pragma unroll
    for (int p = 0; p < 16; ++p) { S1[p] = 0.f; S2[p] = 0.f; }
    float rs = 0.f;

#pragma unroll 1
    for (int j = 0; j < 18; ++j) {
      const int n = ng + (j << 4);
      float V[16];
      compute_votes(Wt, xp_s, n, o, V);

      float ra;
      if (it == 0) {
        ra = a_s[n] * (1.0f/32.0f);
      } else {
        // logp = -0.5 * ( sum_p (V-mu)^2*isig + slog )
        float q = slog_r;
#pragma unroll
        for (int p = 0; p < 16; ++p) {
          const float d = V[p] - mu_r[p];
          q = fmaf(d*d, isig_r[p], q);
        }
        float z = la_r - 0.5f*q;
        // softmax over the 32 o's (one half-wave holds all o for this n)
        float m = z;
#pragma unroll
        for (int msk = 16; msk >= 1; msk >>= 1) m = fmaxf(m, __shfl_xor(m, msk));
        float ev = expf(z - m);
        float s = ev;
#pragma unroll
        for (int msk = 16; msk >= 1; msk >>= 1) s += __shfl_xor(s, msk);
        ra = (ev / s) * a_s[n];
      }
      rs += ra;
#pragma unroll
      for (int p = 0; p < 16; ++p) {
        const float rv = ra * V[p];
        S1[p] += rv;
        S2[p] = fmaf(rv, V[p], S2[p]);
      }
    }

    // ---- reduce: pair-combine ng via lane^32, then 8 wave-partials in LDS
#pragma unroll
    for (int p = 0; p < 16; ++p) {
      S1[p] += __shfl_xor(S1[p], 32);
      S2[p] += __shfl_xor(S2[p], 32);
    }
    rs += __shfl_xor(rs, 32);
    if (lane < 32) {
      float* p1 = part1 + wv*544 + o*17;
      float* p2 = part2 + wv*544 + o*17;
#pragma unroll
      for (int p = 0; p < 16; ++p) { p1[p] = S1[p]; p2[p] = S2[p]; }
      prs[wv*32 + o] = rs;
    }
    __syncthreads();

    // ---- E1: mu, sig2 per (o,p)   (fused: var = s2/rs - mu^2, clamped)
    {
      const int pi = t >> 5, oo = t & 31;   // t < 512 covers all (p,o)
      float s1 = 0.f, s2 = 0.f, rsum = EPSV;
#pragma unroll
      for (int g = 0; g < 8; ++g) {
        s1   += part1[g*544 + oo*17 + pi];
        s2   += part2[g*544 + oo*17 + pi];
        rsum += prs[(g << 5) + oo];
      }
      const float mu = s1 / rsum;
      float var = s2 / rsum - mu*mu;
      var = fmaxf(var, 0.f);
      const float sg = var + EPSV;
      mu_t[pi*32 + oo]   = mu;
      isig_t[pi*32 + oo] = 1.0f / sg;
      lsig_t[pi*32 + oo] = logf(sg);
    }
    __syncthreads();

    // ---- E2: cost, a_out per o
    if (t < 32) {
      float rsum = EPSV;
#pragma unroll
      for (int g = 0; g < 8; ++g) rsum += prs[(g << 5) + t];
      float slog = 0.f;
#pragma unroll
      for (int p = 0; p < 16; ++p) slog += lsig_t[p*32 + t];
      const float bu = Bu[t];
      const float ba = Ba[t];
      const float cost = rsum * (16.0f*bu + 0.5f*slog);
      const float av = 1.0f / (1.0f + expf(-(ba - cost)));   // LAM=1
      aout_s[t] = av;
      la_s[t]   = logf(av + EPSV);
      slog_s[t] = slog;
    }
    __syncthreads();

    if (it < 2) {
#pragma unroll
      for (int p = 0; p < 16; ++p) {
        mu_r[p]   = mu_t[p*32 + o];
        isig_r[p] = isig_t[p*32 + o];
      }
      slog_r = slog_s[o];
      la_r   = la_s[o];
    }
  }

  // ---- outputs (fp32): pose = mu (B,Ho,Wo,OC,M,M) then a_out (B,Ho,Wo,OC)
  {
    const int oo = t >> 4, pi = t & 15;     // t < 512
    Out[pos*512 + t] = mu_t[pi*32 + oo];
  }
  if (t < 32) Out[294912 + pos*32 + t] = aout_s[t];
}

extern "C" void kernel_launch(void* const* d_in, const int* in_sizes, int n_in,
                              void* d_out, int out_size, void* d_ws, size_t ws_size,
                              hipStream_t stream) {
  (void)in_sizes; (void)n_in; (void)d_ws; (void)ws_size; (void)out_size;
  const float* X  = (const float*)d_in[0];
  const float* A  = (const float*)d_in[1];
  const float* Wt = (const float*)d_in[2];
  const float* Bu = (const float*)d_in[3];
  const float* Ba = (const float*)d_in[4];
  float* Out = (float*)d_out;
  hipLaunchKernelGGL(caps_em_kernel, dim3(576), dim3(512), 0, stream,
                     X, A, Wt, Bu, Ba, Out);
}